// Round 6
// baseline (356.942 us; speedup 1.0000x reference)
//
#include <hip/hip_runtime.h>
#include <hip/hip_bf16.h>
#include <stdint.h>

// GeoSemNodeEm: geo = x + (d*x)/d == 2x up to 1-ulp f32 (d = colsum(semantic) ~ 512, never 0).
// out = relu(relu(2x @ W1 + b1) @ W2 + b2) @ Wo + bo via bf16 MFMA.
// N=1024 T=12 C=32 D=64 H=256 O=64; M = N*T*C = 393216 rows.
// Round 6: latency-bound fix -> H processed in quarters (64 h), LDS 16 KB/block,
// __launch_bounds__(256,6) -> 6 blocks/CU (24 waves/CU), grid = 2 exact residency rounds.

using short8 = __attribute__((ext_vector_type(8))) short;   // 8 bf16 (4 VGPRs)
using f32x4  = __attribute__((ext_vector_type(4))) float;

#define NN 1024
#define TT 12
#define CC 32
#define DD 64
#define HH 256
#define OO 64
#define MTOT (NN * TT * CC)

__device__ __forceinline__ short f2bf(float f) {   // scalar cast -> v_cvt_pk_bf16_f32 pairs
    union { __hip_bfloat16 h; short s; } u;
    u.h = __float2bfloat16(f);
    return u.s;
}

// ---- prepack weights as bf16 MFMA B-fragments, fragment-sequential ----
// frag fidx occupies 1024 B: lane l -> 16 B at fidx*1024 + l*16.
// B-frag convention (16x16x32): col n = lane&15, k-slot = 8*(lane>>4) + j.
// fidx 0..31:  W1  (hblk=fidx/2 0..15, ks=fidx&1):  k=d, n=h
// fidx 32..63: W2  (nt2=f/8, ksg=f&7):              k=h, n=o
// fidx 64..71: Wo  (nt3=f/2, ks3=f&1):              k=o1, n=o2
__global__ void prepack_kernel(const float* __restrict__ W1, const float* __restrict__ W2,
                               const float* __restrict__ Wo, unsigned short* __restrict__ wf) {
    int fidx = blockIdx.x;   // 72
    int l = threadIdx.x;     // 64
    int r = l & 15, g = l >> 4;
    unsigned short vals[8];
    if (fidx < 32) {
        int hblk = fidx >> 1, ks = fidx & 1;
        #pragma unroll
        for (int j = 0; j < 8; ++j) {
            int d = ks * 32 + g * 8 + j, h = hblk * 16 + r;
            vals[j] = (unsigned short)f2bf(W1[d * HH + h]);
        }
    } else if (fidx < 64) {
        int f = fidx - 32, nt2 = f >> 3, ksg = f & 7;
        #pragma unroll
        for (int j = 0; j < 8; ++j) {
            int h = ksg * 32 + g * 8 + j, o = nt2 * 16 + r;
            vals[j] = (unsigned short)f2bf(W2[h * OO + o]);
        }
    } else {
        int f = fidx - 64, nt3 = f >> 1, ks3 = f & 1;
        #pragma unroll
        for (int j = 0; j < 8; ++j) {
            int o1 = ks3 * 32 + g * 8 + j, o2 = nt3 * 16 + r;
            vals[j] = (unsigned short)f2bf(Wo[o1 * OO + o2]);
        }
    }
    unsigned short* dst = wf + (size_t)fidx * 512 + l * 8;
    #pragma unroll
    for (int j = 0; j < 8; ++j) dst[j] = vals[j];
}

// ---- fused MLP: 4 waves/block, 32 rows/wave, per-wave 4 KB LDS tile [32 m][64] bf16 ----
// Swizzle (128 B row stride): byte = m*128 + ((c*2) ^ ((m&7)<<4)) for element column c.
// Write (c = nt*16+r): offs = (nt*32 + 2r) ^ ((m&7)<<4).
// Read 16 B A-frag (c0 = kq*32+g*8): offs = (kq*64 + g*16) ^ ((row&7)<<4) — 16-aligned, XOR
// on bits 4..6 only => chunk stays contiguous; lanes r..r+8 alias 2/bank => conflict-free.
__launch_bounds__(256, 6)
__global__ void fused_mlp_kernel(const float* __restrict__ x,
                                 const unsigned short* __restrict__ wf,
                                 const float* __restrict__ b1, const float* __restrict__ b2,
                                 const float* __restrict__ bo, float* __restrict__ out) {
    __shared__ short sBuf[4][32 * 64];   // 4 KB per wave, 16 KB per block
    const int tid = threadIdx.x;
    const int w = tid >> 6, l = tid & 63;
    const int r = l & 15, g = l >> 4;
    const int m0 = (blockIdx.x * 4 + w) * 32;

    // A1 fragments: 2x, k = d. A-frag: row m = lane&15, k-slot = 8*(lane>>4)+j.
    short8 a1[2][2];
    #pragma unroll
    for (int ms = 0; ms < 2; ++ms) {
        #pragma unroll
        for (int ks = 0; ks < 2; ++ks) {
            const float* px = x + (size_t)(m0 + ms * 16 + r) * DD + ks * 32 + g * 8;
            float4 u0 = *(const float4*)px;
            float4 u1 = *(const float4*)(px + 4);
            float vv[8] = {u0.x, u0.y, u0.z, u0.w, u1.x, u1.y, u1.z, u1.w};
            short8 a;
            #pragma unroll
            for (int j = 0; j < 8; ++j) a[j] = f2bf(2.0f * vv[j]);
            a1[ms][ks] = a;
        }
    }

    const short8* wf8 = (const short8*)wf;
    short* myH = sBuf[w];
    f32x4 acc2[2][4] = {};   // layer-2 accumulators over all 64 o, k accumulated across quarters

    #pragma unroll
    for (int q = 0; q < 4; ++q) {
        // ---- layer 1, this h-quarter (64 h): 4 nt blocks ----
        #pragma unroll
        for (int nt = 0; nt < 4; ++nt) {
            int hblk = q * 4 + nt;                       // global 16-h block
            f32x4 acc0 = {0.f, 0.f, 0.f, 0.f}, accA = {0.f, 0.f, 0.f, 0.f};
            #pragma unroll
            for (int ks = 0; ks < 2; ++ks) {
                short8 bfr = wf8[(hblk * 2 + ks) * 64 + l];
                acc0 = __builtin_amdgcn_mfma_f32_16x16x32_bf16(a1[0][ks], bfr, acc0, 0, 0, 0);
                accA = __builtin_amdgcn_mfma_f32_16x16x32_bf16(a1[1][ks], bfr, accA, 0, 0, 0);
            }
            float bias = b1[hblk * 16 + r];
            #pragma unroll
            for (int ms = 0; ms < 2; ++ms) {
                f32x4 acc = ms ? accA : acc0;
                #pragma unroll
                for (int reg = 0; reg < 4; ++reg) {
                    float v = acc[reg] + bias;           // C/D: col=lane&15(h), row=4*(l>>4)+reg(m)
                    v = v > 0.f ? v : 0.f;
                    int m = ms * 16 + 4 * g + reg;
                    int addr = m * 128 + ((nt * 32 + 2 * r) ^ ((m & 7) << 4));
                    myH[addr >> 1] = f2bf(v);
                }
            }
        }
        asm volatile("s_waitcnt lgkmcnt(0)" ::: "memory");
        // ---- A2 fragments from this quarter (k = q*64 + kq*32 + g*8 + j) ----
        short8 a2[2][2];
        #pragma unroll
        for (int ms = 0; ms < 2; ++ms) {
            #pragma unroll
            for (int kq = 0; kq < 2; ++kq) {
                int row = ms * 16 + r;
                int addr = row * 128 + ((kq * 64 + g * 16) ^ ((row & 7) << 4));
                a2[ms][kq] = *reinterpret_cast<const short8*>(myH + (addr >> 1));
            }
        }
        // ---- layer 2 partial accumulate (this quarter's 64 k) ----
        #pragma unroll
        for (int nt2 = 0; nt2 < 4; ++nt2) {
            #pragma unroll
            for (int kq = 0; kq < 2; ++kq) {
                short8 bfr = wf8[(32 + nt2 * 8 + q * 2 + kq) * 64 + l];   // ksg = q*2+kq
                acc2[0][nt2] = __builtin_amdgcn_mfma_f32_16x16x32_bf16(a2[0][kq], bfr, acc2[0][nt2], 0, 0, 0);
                acc2[1][nt2] = __builtin_amdgcn_mfma_f32_16x16x32_bf16(a2[1][kq], bfr, acc2[1][nt2], 0, 0, 0);
            }
        }
        // next quarter's ds_writes are same-wave in-order after these reads; MFMA consumption
        // forces the compiler's lgkmcnt wait, so no extra WAR fence needed.
    }

    // ---- bias2 + relu -> h2 tile (reuses sBuf; all sBuf readers completed above) ----
    #pragma unroll
    for (int nt2 = 0; nt2 < 4; ++nt2) {
        float bias = b2[nt2 * 16 + r];
        #pragma unroll
        for (int ms = 0; ms < 2; ++ms) {
            #pragma unroll
            for (int reg = 0; reg < 4; ++reg) {
                float v = acc2[ms][nt2][reg] + bias;
                v = v > 0.f ? v : 0.f;
                int m = ms * 16 + 4 * g + reg;
                int addr = m * 128 + ((nt2 * 32 + 2 * r) ^ ((m & 7) << 4));
                myH[addr >> 1] = f2bf(v);
            }
        }
    }
    asm volatile("s_waitcnt lgkmcnt(0)" ::: "memory");
    // ---- layer 3 ----
    short8 a3[2][2];
    #pragma unroll
    for (int ms = 0; ms < 2; ++ms) {
        #pragma unroll
        for (int k3 = 0; k3 < 2; ++k3) {
            int row = ms * 16 + r;
            int addr = row * 128 + ((k3 * 64 + g * 16) ^ ((row & 7) << 4));
            a3[ms][k3] = *reinterpret_cast<const short8*>(myH + (addr >> 1));
        }
    }
    f32x4 cc[2][4];
    #pragma unroll
    for (int nt3 = 0; nt3 < 4; ++nt3) {
        f32x4 c0 = {0.f, 0.f, 0.f, 0.f}, c1 = {0.f, 0.f, 0.f, 0.f};
        #pragma unroll
        for (int k3 = 0; k3 < 2; ++k3) {
            short8 bfr = wf8[(64 + nt3 * 2 + k3) * 64 + l];
            c0 = __builtin_amdgcn_mfma_f32_16x16x32_bf16(a3[0][k3], bfr, c0, 0, 0, 0);
            c1 = __builtin_amdgcn_mfma_f32_16x16x32_bf16(a3[1][k3], bfr, c1, 0, 0, 0);
        }
        float bias = bo[nt3 * 16 + r];
        #pragma unroll
        for (int reg = 0; reg < 4; ++reg) { cc[0][nt3][reg] = c0[reg] + bias; cc[1][nt3][reg] = c1[reg] + bias; }
    }
    // ---- stores: (ms,reg) outer so 4 consecutive dword stores complete full 256 B rows ----
    #pragma unroll
    for (int ms = 0; ms < 2; ++ms) {
        #pragma unroll
        for (int reg = 0; reg < 4; ++reg) {
            size_t rowbase = (size_t)(m0 + ms * 16 + 4 * g + reg) * OO;
            #pragma unroll
            for (int nt3 = 0; nt3 < 4; ++nt3)
                out[rowbase + nt3 * 16 + r] = cc[ms][nt3][reg];
        }
    }
}

extern "C" void kernel_launch(void* const* d_in, const int* in_sizes, int n_in,
                              void* d_out, int out_size, void* d_ws, size_t ws_size,
                              hipStream_t stream) {
    const float* x   = (const float*)d_in[0];
    // d_in[1] (semantic_data) intentionally unused: x + (d*x)/d == 2x to 1 ulp, d never 0.
    const float* W1  = (const float*)d_in[2];
    const float* b1  = (const float*)d_in[3];
    const float* W2  = (const float*)d_in[4];
    const float* b2  = (const float*)d_in[5];
    const float* Wo  = (const float*)d_in[6];
    const float* bo  = (const float*)d_in[7];
    float* out = (float*)d_out;

    unsigned short* wf = (unsigned short*)d_ws;   // 72 KB weight fragments

    prepack_kernel<<<dim3(72), dim3(64), 0, stream>>>(W1, W2, Wo, wf);
    fused_mlp_kernel<<<dim3(MTOT / 128), dim3(256), 0, stream>>>(x, wf, b1, b2, bo, out);
}

// Round 9
// 255.002 us; speedup vs baseline: 1.3998x; 1.3998x over previous
//
#include <hip/hip_runtime.h>
#include <hip/hip_bf16.h>
#include <stdint.h>

// GeoSemNodeEm: geo = x + (d*x)/d == 2x up to 1-ulp f32 (d = colsum(semantic) ~ 512, never 0).
// out = relu(relu(2x @ W1 + b1) @ W2 + b2) @ Wo + bo via bf16 MFMA.
// N=1024 T=12 C=32 D=64 H=256 O=64; M = N*T*C = 393216 rows.
// Round 7/8 (resubmit x2): round-6 body, but __launch_bounds__(256,4) — (256,6) forced VGPR
// 64->40 and spilled ~560 MB of scratch (FETCH 306/WRITE 507 MB, dur 217us). 16 KB LDS keeps
// the LDS ceiling at 10 blocks/CU; at 64 VGPR the wave ceiling (8/SIMD) binds instead.

using short8 = __attribute__((ext_vector_type(8))) short;   // 8 bf16 (4 VGPRs)
using f32x4  = __attribute__((ext_vector_type(4))) float;

#define NN 1024
#define TT 12
#define CC 32
#define DD 64
#define HH 256
#define OO 64
#define MTOT (NN * TT * CC)

__device__ __forceinline__ short f2bf(float f) {   // scalar cast -> v_cvt_pk_bf16_f32 pairs
    union { __hip_bfloat16 h; short s; } u;
    u.h = __float2bfloat16(f);
    return u.s;
}

// ---- prepack weights as bf16 MFMA B-fragments, fragment-sequential ----
// frag fidx occupies 1024 B: lane l -> 16 B at fidx*1024 + l*16.
// B-frag convention (16x16x32): col n = lane&15, k-slot = 8*(lane>>4) + j.
// fidx 0..31:  W1  (hblk=fidx/2 0..15, ks=fidx&1):  k=d, n=h
// fidx 32..63: W2  (nt2=f/8, ksg=f&7):              k=h, n=o
// fidx 64..71: Wo  (nt3=f/2, ks3=f&1):              k=o1, n=o2
__global__ void prepack_kernel(const float* __restrict__ W1, const float* __restrict__ W2,
                               const float* __restrict__ Wo, unsigned short* __restrict__ wf) {
    int fidx = blockIdx.x;   // 72
    int l = threadIdx.x;     // 64
    int r = l & 15, g = l >> 4;
    unsigned short vals[8];
    if (fidx < 32) {
        int hblk = fidx >> 1, ks = fidx & 1;
        #pragma unroll
        for (int j = 0; j < 8; ++j) {
            int d = ks * 32 + g * 8 + j, h = hblk * 16 + r;
            vals[j] = (unsigned short)f2bf(W1[d * HH + h]);
        }
    } else if (fidx < 64) {
        int f = fidx - 32, nt2 = f >> 3, ksg = f & 7;
        #pragma unroll
        for (int j = 0; j < 8; ++j) {
            int h = ksg * 32 + g * 8 + j, o = nt2 * 16 + r;
            vals[j] = (unsigned short)f2bf(W2[h * OO + o]);
        }
    } else {
        int f = fidx - 64, nt3 = f >> 1, ks3 = f & 1;
        #pragma unroll
        for (int j = 0; j < 8; ++j) {
            int o1 = ks3 * 32 + g * 8 + j, o2 = nt3 * 16 + r;
            vals[j] = (unsigned short)f2bf(Wo[o1 * OO + o2]);
        }
    }
    unsigned short* dst = wf + (size_t)fidx * 512 + l * 8;
    #pragma unroll
    for (int j = 0; j < 8; ++j) dst[j] = vals[j];
}

// ---- fused MLP: 4 waves/block, 32 rows/wave, per-wave 4 KB LDS tile [32 m][64] bf16 ----
// Swizzle (128 B row stride): byte = m*128 + ((c*2) ^ ((m&7)<<4)) for element column c.
// Write (c = nt*16+r): offs = (nt*32 + 2r) ^ ((m&7)<<4).
// Read 16 B A-frag (c0 = kq*32+g*8): offs = (kq*64 + g*16) ^ ((row&7)<<4) — 16-aligned, XOR
// on bits 4..6 only => chunk stays contiguous; verified conflict-free (R6: SQ_LDS_BANK_CONFLICT=0).
__launch_bounds__(256, 4)
__global__ void fused_mlp_kernel(const float* __restrict__ x,
                                 const unsigned short* __restrict__ wf,
                                 const float* __restrict__ b1, const float* __restrict__ b2,
                                 const float* __restrict__ bo, float* __restrict__ out) {
    __shared__ short sBuf[4][32 * 64];   // 4 KB per wave, 16 KB per block
    const int tid = threadIdx.x;
    const int w = tid >> 6, l = tid & 63;
    const int r = l & 15, g = l >> 4;
    const int m0 = (blockIdx.x * 4 + w) * 32;

    // A1 fragments: 2x, k = d. A-frag: row m = lane&15, k-slot = 8*(lane>>4)+j.
    short8 a1[2][2];
    #pragma unroll
    for (int ms = 0; ms < 2; ++ms) {
        #pragma unroll
        for (int ks = 0; ks < 2; ++ks) {
            const float* px = x + (size_t)(m0 + ms * 16 + r) * DD + ks * 32 + g * 8;
            float4 u0 = *(const float4*)px;
            float4 u1 = *(const float4*)(px + 4);
            float vv[8] = {u0.x, u0.y, u0.z, u0.w, u1.x, u1.y, u1.z, u1.w};
            short8 a;
            #pragma unroll
            for (int j = 0; j < 8; ++j) a[j] = f2bf(2.0f * vv[j]);
            a1[ms][ks] = a;
        }
    }

    const short8* wf8 = (const short8*)wf;
    short* myH = sBuf[w];
    f32x4 acc2[2][4] = {};   // layer-2 accumulators over all 64 o, k accumulated across quarters

    #pragma unroll
    for (int q = 0; q < 4; ++q) {
        // ---- layer 1, this h-quarter (64 h): 4 nt blocks ----
        #pragma unroll
        for (int nt = 0; nt < 4; ++nt) {
            int hblk = q * 4 + nt;                       // global 16-h block
            f32x4 acc0 = {0.f, 0.f, 0.f, 0.f}, accA = {0.f, 0.f, 0.f, 0.f};
            #pragma unroll
            for (int ks = 0; ks < 2; ++ks) {
                short8 bfr = wf8[(hblk * 2 + ks) * 64 + l];
                acc0 = __builtin_amdgcn_mfma_f32_16x16x32_bf16(a1[0][ks], bfr, acc0, 0, 0, 0);
                accA = __builtin_amdgcn_mfma_f32_16x16x32_bf16(a1[1][ks], bfr, accA, 0, 0, 0);
            }
            float bias = b1[hblk * 16 + r];
            #pragma unroll
            for (int ms = 0; ms < 2; ++ms) {
                f32x4 acc = ms ? accA : acc0;
                #pragma unroll
                for (int reg = 0; reg < 4; ++reg) {
                    float v = acc[reg] + bias;           // C/D: col=lane&15(h), row=4*(l>>4)+reg(m)
                    v = v > 0.f ? v : 0.f;
                    int m = ms * 16 + 4 * g + reg;
                    int addr = m * 128 + ((nt * 32 + 2 * r) ^ ((m & 7) << 4));
                    myH[addr >> 1] = f2bf(v);
                }
            }
        }
        asm volatile("s_waitcnt lgkmcnt(0)" ::: "memory");
        // ---- A2 fragments from this quarter (k = q*64 + kq*32 + g*8 + j) ----
        short8 a2[2][2];
        #pragma unroll
        for (int ms = 0; ms < 2; ++ms) {
            #pragma unroll
            for (int kq = 0; kq < 2; ++kq) {
                int row = ms * 16 + r;
                int addr = row * 128 + ((kq * 64 + g * 16) ^ ((row & 7) << 4));
                a2[ms][kq] = *reinterpret_cast<const short8*>(myH + (addr >> 1));
            }
        }
        // ---- layer 2 partial accumulate (this quarter's 64 k) ----
        #pragma unroll
        for (int nt2 = 0; nt2 < 4; ++nt2) {
            #pragma unroll
            for (int kq = 0; kq < 2; ++kq) {
                short8 bfr = wf8[(32 + nt2 * 8 + q * 2 + kq) * 64 + l];   // ksg = q*2+kq
                acc2[0][nt2] = __builtin_amdgcn_mfma_f32_16x16x32_bf16(a2[0][kq], bfr, acc2[0][nt2], 0, 0, 0);
                acc2[1][nt2] = __builtin_amdgcn_mfma_f32_16x16x32_bf16(a2[1][kq], bfr, acc2[1][nt2], 0, 0, 0);
            }
        }
        // next quarter's ds_writes are same-wave in-order after these reads; MFMA consumption
        // forces the compiler's lgkmcnt wait, so no extra WAR fence needed.
    }

    // ---- bias2 + relu -> h2 tile (reuses sBuf; all sBuf readers completed above) ----
    #pragma unroll
    for (int nt2 = 0; nt2 < 4; ++nt2) {
        float bias = b2[nt2 * 16 + r];
        #pragma unroll
        for (int ms = 0; ms < 2; ++ms) {
            #pragma unroll
            for (int reg = 0; reg < 4; ++reg) {
                float v = acc2[ms][nt2][reg] + bias;
                v = v > 0.f ? v : 0.f;
                int m = ms * 16 + 4 * g + reg;
                int addr = m * 128 + ((nt2 * 32 + 2 * r) ^ ((m & 7) << 4));
                myH[addr >> 1] = f2bf(v);
            }
        }
    }
    asm volatile("s_waitcnt lgkmcnt(0)" ::: "memory");
    // ---- layer 3 ----
    short8 a3[2][2];
    #pragma unroll
    for (int ms = 0; ms < 2; ++ms) {
        #pragma unroll
        for (int k3 = 0; k3 < 2; ++k3) {
            int row = ms * 16 + r;
            int addr = row * 128 + ((k3 * 64 + g * 16) ^ ((row & 7) << 4));
            a3[ms][k3] = *reinterpret_cast<const short8*>(myH + (addr >> 1));
        }
    }
    f32x4 cc[2][4];
    #pragma unroll
    for (int nt3 = 0; nt3 < 4; ++nt3) {
        f32x4 c0 = {0.f, 0.f, 0.f, 0.f}, c1 = {0.f, 0.f, 0.f, 0.f};
        #pragma unroll
        for (int k3 = 0; k3 < 2; ++k3) {
            short8 bfr = wf8[(64 + nt3 * 2 + k3) * 64 + l];
            c0 = __builtin_amdgcn_mfma_f32_16x16x32_bf16(a3[0][k3], bfr, c0, 0, 0, 0);
            c1 = __builtin_amdgcn_mfma_f32_16x16x32_bf16(a3[1][k3], bfr, c1, 0, 0, 0);
        }
        float bias = bo[nt3 * 16 + r];
        #pragma unroll
        for (int reg = 0; reg < 4; ++reg) { cc[0][nt3][reg] = c0[reg] + bias; cc[1][nt3][reg] = c1[reg] + bias; }
    }
    // ---- stores: (ms,reg) outer so 4 consecutive dword stores complete full 256 B rows ----
    #pragma unroll
    for (int ms = 0; ms < 2; ++ms) {
        #pragma unroll
        for (int reg = 0; reg < 4; ++reg) {
            size_t rowbase = (size_t)(m0 + ms * 16 + 4 * g + reg) * OO;
            #pragma unroll
            for (int nt3 = 0; nt3 < 4; ++nt3)
                out[rowbase + nt3 * 16 + r] = cc[ms][nt3][reg];
        }
    }
}

extern "C" void kernel_launch(void* const* d_in, const int* in_sizes, int n_in,
                              void* d_out, int out_size, void* d_ws, size_t ws_size,
                              hipStream_t stream) {
    const float* x   = (const float*)d_in[0];
    // d_in[1] (semantic_data) intentionally unused: x + (d*x)/d == 2x to 1 ulp, d never 0.
    const float* W1  = (const float*)d_in[2];
    const float* b1  = (const float*)d_in[3];
    const float* W2  = (const float*)d_in[4];
    const float* b2  = (const float*)d_in[5];
    const float* Wo  = (const float*)d_in[6];
    const float* bo  = (const float*)d_in[7];
    float* out = (float*)d_out;

    unsigned short* wf = (unsigned short*)d_ws;   // 72 KB weight fragments

    prepack_kernel<<<dim3(72), dim3(64), 0, stream>>>(W1, W2, Wo, wf);
    fused_mlp_kernel<<<dim3(MTOT / 128), dim3(256), 0, stream>>>(x, wf, b1, b2, bo, out);
}